// Round 1
// baseline (118.967 us; speedup 1.0000x reference)
//
#include <hip/hip_runtime.h>

// RandomDropout: B=8192 rows, S=2048 cols, int32 tokens.
// Odd rows with n_tokens>=10: drop argmin(uniform(key(42))) among first
// n_tokens, compact left, zero tail. Else: passthrough.
//
// PRNG: JAX partitionable threefry (confirmed R1): bits(i) =
//   threefry2x32(key=(0,42), c0=0, c1=i).out0 ^ .out1
//
// R4 design (on top of R3):
//  - Tail-read elision: rows are zero-padded prefixes (mean ntok~1026 of
//    2048), so ~45% of all reads were known-zero bytes. Probe element
//    256k per chunk (lanes 0..7, one ballot): chunk k is all-zero iff
//    in[256k]==0. Bulk-load only the first nchunks chunks; substitute 0
//    for the rest. All consumers (apply test, argmin mask e[c]>0,
//    successor chain nx, shifted store, zero-tail store) are correct
//    with v[k]=0, since those elements ARE 0 in the input.
//    Writes unchanged (output is poisoned; full row must be stored).
//    Expected: FETCH_SIZE 64MiB -> ~37MiB, kernel -5..7 us.
//  - nchunks is wave-uniform (ballot -> sgpr), so chunk guards are
//    scalar branches and skipped loads are never issued.
//  - R3 carried forward: no token count (ntok>=10 <=> in[row,9]>0),
//    homogeneous even/odd block halves, __launch_bounds__(256,8).

constexpr int S = 2048;
constexpr int BLOCK = 256;           // 4 waves; 1 row per wave
constexpr int CHUNKS = S / 4 / 64;   // 8 int4 per lane

__device__ __forceinline__ unsigned rotl32(unsigned x, int r) {
    return (x << r) | (x >> (32 - r));
}

// Threefry-2x32, 20 rounds, key = (0, 42); returns out0 ^ out1.
__device__ __forceinline__ unsigned prng_bits(unsigned flat_idx) {
    const unsigned ks0 = 0u;
    const unsigned ks1 = 42u;
    const unsigned ks2 = 0x1BD11BDAu ^ ks0 ^ ks1;
    unsigned x0 = 0u + ks0;
    unsigned x1 = flat_idx + ks1;
#define TF_R4(a, b, c, d)                                   \
    x0 += x1; x1 = rotl32(x1, a); x1 ^= x0;                 \
    x0 += x1; x1 = rotl32(x1, b); x1 ^= x0;                 \
    x0 += x1; x1 = rotl32(x1, c); x1 ^= x0;                 \
    x0 += x1; x1 = rotl32(x1, d); x1 ^= x0;
    TF_R4(13, 15, 26, 6)   x0 += ks1; x1 += ks2 + 1u;
    TF_R4(17, 29, 16, 24)  x0 += ks2; x1 += ks0 + 2u;
    TF_R4(13, 15, 26, 6)   x0 += ks0; x1 += ks1 + 3u;
    TF_R4(17, 29, 16, 24)  x0 += ks1; x1 += ks2 + 4u;
    TF_R4(13, 15, 26, 6)   x0 += ks2; x1 += ks0 + 5u;
#undef TF_R4
    return x0 ^ x1;
}

__global__ __launch_bounds__(BLOCK, 8) void random_dropout_kernel(
    const int* __restrict__ in, int* __restrict__ out) {
    const int wave = threadIdx.x >> 6;
    const int lane = threadIdx.x & 63;
    const int nb_even = (int)(gridDim.x >> 1);
    const bool odd_block = (int)blockIdx.x >= nb_even;

    // Homogeneous row mapping: even blocks -> even rows, odd -> odd rows.
    const int slot = odd_block ? ((int)blockIdx.x - nb_even) : (int)blockIdx.x;
    const int b = 2 * (4 * slot + wave) + (odd_block ? 1 : 0);
    const size_t base = (size_t)b * S;
    const int4* vin = (const int4*)(in + base);
    int4* vout = (int4*)(out + base);

    // Probe: chunk k covers elements [256k, 256k+256). Prefix-zero rows =>
    // chunk k is entirely zero iff in[256k]==0. One 4B load on lanes 0..7,
    // one ballot; nchunks = count of leading nonzero probes (wave-uniform).
    int probe = 0;
    if (lane < CHUNKS) probe = in[base + ((size_t)lane << 8)];
    const unsigned long long pm = __ballot(probe > 0);
    const int nchunks = (int)__builtin_ctzll(~pm);   // <= 8 (bit 8 of ~pm set)

    if (!odd_block) {
        // Streaming copy of the nonzero prefix; zero-fill the tail without
        // reading it. Stores stay full-row (output buffer is poisoned).
#pragma unroll
        for (int k = 0; k < CHUNKS; k++) {
            int4 t = make_int4(0, 0, 0, 0);
            if (k < nchunks) t = vin[lane + 64 * k];
            vout[lane + 64 * k] = t;
        }
        return;
    }

    // Odd row: load only the chunks that can contain tokens.
    int4 v[CHUNKS];
#pragma unroll
    for (int k = 0; k < CHUNKS; k++) {
        v[k] = make_int4(0, 0, 0, 0);
        if (k < nchunks) v[k] = vin[lane + 64 * k];
    }

    // apply <=> ntok >= 10 <=> in[row,9] > 0. Position 9 = 4*2+1 -> lane 2,
    // chunk 0, component .y. (Chunk 0 is always loaded: ntok >= 5.)
    const bool apply = __shfl(v[0].y, 2, 64) > 0;

    if (!apply) {
#pragma unroll
        for (int k = 0; k < CHUNKS; k++) vout[lane + 64 * k] = v[k];
        return;
    }

    // Argmin of uniform over valid positions (token > 0 <=> s < ntok).
    // uniform value is monotone in (bits >> 9); pack (mant23<<11 | s) so
    // ties break to the lowest index (matches stable top_k).
    unsigned long long best = ~0ull;
    const unsigned rowbase = (unsigned)b * (unsigned)S;
#pragma unroll
    for (int k = 0; k < CHUNKS; k++) {
        if (k < nchunks) {   // wave-uniform: zero chunks have no valid tokens
            const int s0 = 4 * (lane + 64 * k);
            const int* e = (const int*)&v[k];
#pragma unroll
            for (int c = 0; c < 4; c++) {
                if (e[c] > 0) {
                    const unsigned bits = prng_bits(rowbase + (unsigned)(s0 + c));
                    const unsigned long long comb =
                        ((unsigned long long)(bits >> 9) << 11) |
                        (unsigned)(s0 + c);
                    best = comb < best ? comb : best;
                }
            }
        }
    }
#pragma unroll
    for (int off = 32; off; off >>= 1) {
        const unsigned long long o = __shfl_down(best, off, 64);
        best = o < best ? o : best;
    }
    const int drop = (int)(__shfl(best, 0, 64) & 0x7FFull);

    // Successor of each int4's last element (element 4*(g+1)):
    //   lanes 0..62: lane+1's v[k].x ; lane 63: lane 0's v[k+1].x ;
    //   lane 63 chunk 7: element 2048 -> 0. Unloaded chunks are v=0, which
    //   matches the input (those elements are genuinely zero).
    int nx[CHUNKS];
#pragma unroll
    for (int k = 0; k < CHUNKS; k++) {
        const int a = __shfl_down(v[k].x, 1, 64);
        const int bb = (k < CHUNKS - 1) ? __shfl(v[k + 1].x, 0, 64) : 0;
        nx[k] = (lane == 63) ? bb : a;
    }

    // out[j] = j < drop ? in[j] : in[j+1]  (tail zeros free: prefix-zero
    // input gives in[j+1]==0 for j >= ntok-1).
#pragma unroll
    for (int k = 0; k < CHUNKS; k++) {
        const int j0 = 4 * (lane + 64 * k);
        int4 o;
        o.x = (j0 + 0 < drop) ? v[k].x : v[k].y;
        o.y = (j0 + 1 < drop) ? v[k].y : v[k].z;
        o.z = (j0 + 2 < drop) ? v[k].z : v[k].w;
        o.w = (j0 + 3 < drop) ? v[k].w : nx[k];
        vout[lane + 64 * k] = o;
    }
}

extern "C" void kernel_launch(void* const* d_in, const int* in_sizes, int n_in,
                              void* d_out, int out_size, void* d_ws, size_t ws_size,
                              hipStream_t stream) {
    const int* in = (const int*)d_in[0];
    int* out = (int*)d_out;
    const int total = in_sizes[0];               // B * S
    const int B = total / S;                     // 8192
    random_dropout_kernel<<<B / 4, BLOCK, 0, stream>>>(in, out);
}